// Round 2
// baseline (230.784 us; speedup 1.0000x reference)
//
#include <hip/hip_runtime.h>
#include <hip/hip_bf16.h>
#include <stdint.h>

// ---------------------------------------------------------------------------
// CustomConvLayer: out[b,o,h,w] = sum_{c,dh,dw} xpad[b,c,h+dh,w+dw] * W[o,c,dh*3+dw]
// Implicit-im2col GEMM, bf16 MFMA 16x16x32. M=B*H*W, N=128, K=576.
//
// R5: FUSED single-pass conv. Counter evidence (R4): timed region is dominated
// by two 512-MiB harness poison fills (2x81us); our kernels total ~59us. The
// xpad intermediate (34.6MB W + ~60MB R + a launch) existed only to transpose
// NCHW->NHWC. This version deletes it: each block (b,h) stages its 3 x-rows
// straight from NCHW fp32 via a small double-buffered LDS transpose tile
// (T[2][64][40]) into the XOR-swizzled bf16 Aslab, then runs the proven R3
// 18-step barrier-free MFMA loop verbatim. 3x row redundancy across blocks is
// L2-served (adjacent h on same XCD, ~3MB working set < 4MB L2). Nontemporal
// epilogue stores keep dead out-writes from evicting x rows in L2.
// No forced launch bound (R4's (512,4) forced VGPR<=128 < working set -> spills).
// LDS 60.2KB -> 2 blocks/CU: one block's read phase overlaps the other's writes.
// ---------------------------------------------------------------------------

typedef __bf16 bf16x8 __attribute__((ext_vector_type(8)));
typedef float  f32x4  __attribute__((ext_vector_type(4)));

// ---------------- weights -> fragment-order BtF[s][quad][n] 16B chunks -------
// chunk(s,quad,n)[r] = W[n][c][tap] with k = s*32+quad*8+r, tap=k>>6, c=k&63
__global__ __launch_bounds__(256) void xform_w(const float* __restrict__ wgt,
                                               __bf16* __restrict__ BtF) {
  const int t = blockIdx.x * 256 + threadIdx.x;  // chunk id
  if (t >= 9216) return;
  const int s = t >> 9, rem = t & 511, quad = rem >> 7, n = rem & 127;
  bf16x8 o;
#pragma unroll
  for (int r = 0; r < 8; ++r) {
    const int k = s * 32 + quad * 8 + r;
    const int tap = k >> 6, c = k & 63;
    o[r] = (__bf16)wgt[(n * 64 + c) * 9 + tap];
  }
  *(bf16x8*)(BtF + (size_t)t * 8) = o;
}

// ---------------- fused conv: block=(b,h), stage x->Aslab in-kernel ----------
__global__ __launch_bounds__(256) void conv_mfma(const float* __restrict__ x,
                                                 const __bf16* __restrict__ BtF,
                                                 float* __restrict__ out) {
  __shared__ alignas(16) __bf16 Aslab[3120 * 8];   // 49,920 B: 3 rows x 130 wp x 64 c
  __shared__ alignas(16) __bf16 T[2][64][40];      // 10,240 B transpose tile (stride 40: 16B-aligned rows)
  const int tid  = threadIdx.x;
  const int lane = tid & 63;
  const int wave = tid >> 6;
  const int quad = lane >> 4;
  const int l16  = lane & 15;
  // XCD-aware swizzle: same-XCD blocks get contiguous (b,h) -> x-row L2 reuse
  const int rank = (blockIdx.x & 7) * 256 + (blockIdx.x >> 3);
  const int b = rank >> 7;
  const int h = rank & 127;
  const int wm = wave >> 1;  // M (w) half
  const int wn = wave & 1;   // N half

  // ---- edge chunks wp=0 / wp=129 -> zeros (48 chunks, covered by unit-0 bar)
  if (tid < 48) {
    const int r3 = tid >> 4, wp = ((tid >> 3) & 1) * 129, cq = tid & 7;
    const int v = r3 * 130 + wp;
    const bf16x8 z = {};
    *(bf16x8*)(Aslab + (size_t)(v * 8 + (cq ^ (v & 7))) * 8) = z;
  }

  // ---- staging: 12 units (r3=u>>2 in 0..2, q=u&3 w-quarter), x row xr=h-1+r3
  // load: thread -> (cS = tid>>2, wS = (tid&3)*8): 2 float4 = 8 w at one c
  // gather: thread -> (cqG = tid>>5, wloc = tid&31): one 16B Aslab chunk
  const int cS   = tid >> 2;
  const int wS   = (tid & 3) * 8;
  const int wloc = tid & 31;
  const int cqG  = tid >> 5;
  const float* xc = x + ((size_t)b * 64 + cS) * 16384;  // + xr*128 + q*32 + wS

  f32x4 g[3][2];  // depth-2 prefetch ring; constant-indexed under full unroll

#define XR_OF(u) (h - 1 + ((u) >> 2))
#define ISSUE(u) do {                                                         \
    const int xr_  = XR_OF(u);                                                \
    const int xrc_ = xr_ < 0 ? 0 : (xr_ > 127 ? 127 : xr_);                   \
    const float* p_ = xc + (size_t)xrc_ * 128 + ((u) & 3) * 32 + wS;          \
    g[(u) % 3][0] = *(const f32x4*)p_;                                        \
    g[(u) % 3][1] = *(const f32x4*)(p_ + 4);                                  \
  } while (0)

  ISSUE(0);
  ISSUE(1);
#pragma unroll
  for (int u = 0; u < 12; ++u) {
    if (u < 10) ISSUE(u + 2);
    // consume unit u: zero-substitute out-of-range rows at CONSUME time so the
    // select's vmcnt lands here, not at issue
    {
      const int xr_ = XR_OF(u);
      f32x4 a0 = g[u % 3][0], a1 = g[u % 3][1];
      if (xr_ < 0 || xr_ > 127) { a0 = (f32x4){}; a1 = (f32x4){}; }
      bf16x8 pk;
      pk[0] = (__bf16)a0[0]; pk[1] = (__bf16)a0[1];
      pk[2] = (__bf16)a0[2]; pk[3] = (__bf16)a0[3];
      pk[4] = (__bf16)a1[0]; pk[5] = (__bf16)a1[1];
      pk[6] = (__bf16)a1[2]; pk[7] = (__bf16)a1[3];
      *(bf16x8*)&T[u & 1][cS][wS] = pk;  // byte addr 80*c+2*wS: 16B-aligned
    }
    asm volatile("s_waitcnt lgkmcnt(0)" ::: "memory");
    __builtin_amdgcn_s_barrier();          // raw: in-flight global loads keep flying
    __builtin_amdgcn_sched_barrier(0);
    // gather: transpose-read 8 c at one w, write swizzled Aslab chunk
    {
      bf16x8 o;
#pragma unroll
      for (int j = 0; j < 8; ++j) o[j] = T[u & 1][cqG * 8 + j][wloc];
      const int v = (u >> 2) * 130 + ((u & 3) << 5) + wloc + 1;
      *(bf16x8*)(Aslab + (size_t)(v * 8 + (cqG ^ (v & 7))) * 8) = o;
    }
    // next unit writes the OTHER T buffer; its barrier orders the u+2 reuse
  }
  asm volatile("s_waitcnt lgkmcnt(0)" ::: "memory");
  __builtin_amdgcn_s_barrier();
  __builtin_amdgcn_sched_barrier(0);

  // ---- R3 compute, verbatim: 18 s-steps, no barriers, acc in AGPR/VGPR ----
  f32x4 acc[4][4] = {};
#pragma unroll
  for (int s = 0; s < 18; ++s) {
    const int tap = s >> 1;
    const int dh = tap / 3, dw = tap % 3;
    const int cq = ((s & 1) << 2) + quad;  // 16B chunk index within a 64-elem row
    bf16x8 aF[4], bF[4];                   // plain locals, constant-indexed (SROA)
#pragma unroll
    for (int i = 0; i < 4; ++i) {
      const int m = (wm << 6) + (i << 4) + l16;
      const int v = dh * 130 + m + dw;
      const int slot = (v << 3) + (cq ^ (v & 7));
      aF[i] = *(const bf16x8*)(Aslab + (size_t)slot * 8);
      const int n = (wn << 6) + (i << 4) + l16;
      bF[i] = *(const bf16x8*)(BtF + ((size_t)((s * 4 + quad) * 128 + n) << 3));
    }
#pragma unroll
    for (int i = 0; i < 4; ++i)
#pragma unroll
      for (int j = 0; j < 4; ++j)
        acc[i][j] = __builtin_amdgcn_mfma_f32_16x16x32_bf16(aF[i], bF[j], acc[i][j], 0, 0, 0);
  }

  // epilogue: D col = lane&15 = n, row = quad*4+reg = m (out w). Nontemporal:
  // out is write-once/dead -> don't evict x rows from L2.
#pragma unroll
  for (int j = 0; j < 4; ++j) {
    const int n = (wn << 6) + (j << 4) + l16;
    float* orow = out + (((size_t)(b * 128 + n) * 128 + h) << 7);
#pragma unroll
    for (int i = 0; i < 4; ++i) {
      const int m0 = (wm << 6) + (i << 4) + (quad << 2);
      __builtin_nontemporal_store(acc[i][j], (f32x4*)(orow + m0));
    }
  }
}

// ---------------- fallback (if workspace too small): direct fp32 conv -------
__global__ void conv_naive(const float* __restrict__ x, const float* __restrict__ wgt,
                           float* __restrict__ out, int total) {
  int idx = blockIdx.x * 256 + threadIdx.x;
  if (idx >= total) return;
  const int w = idx & 127;
  const int h = (idx >> 7) & 127;
  const int o = (idx >> 14) & 127;
  const int b = idx >> 21;
  float s = 0.f;
  for (int c = 0; c < 64; ++c) {
    const float* xc = x + ((size_t)(b * 64 + c) * 128) * 128;
    const float* wc = wgt + (o * 64 + c) * 9;
    for (int dh = 0; dh < 3; ++dh) {
      const int hh = h + dh - 1;
      if (hh < 0 || hh >= 128) continue;
      for (int dw = 0; dw < 3; ++dw) {
        const int ww = w + dw - 1;
        if (ww < 0 || ww >= 128) continue;
        s += xc[hh * 128 + ww] * wc[dh * 3 + dw];
      }
    }
  }
  out[idx] = s;
}

extern "C" void kernel_launch(void* const* d_in, const int* in_sizes, int n_in,
                              void* d_out, int out_size, void* d_ws, size_t ws_size,
                              hipStream_t stream) {
  const float* x   = (const float*)d_in[0];
  const float* wgt = (const float*)d_in[1];
  float* out = (float*)d_out;

  const size_t BTF_BYTES = 9216ull * 16;  // 147456 (L2-resident)

  if (ws_size < BTF_BYTES) {
    const int total = 16 * 128 * 128 * 128;
    conv_naive<<<(total + 255) / 256, 256, 0, stream>>>(x, wgt, out, total);
    return;
  }

  __bf16* BtF = (__bf16*)d_ws;

  xform_w<<<36, 256, 0, stream>>>(wgt, BtF);
  conv_mfma<<<2048, 256, 0, stream>>>(x, BtF, out);
}

// Round 3
// 215.624 us; speedup vs baseline: 1.0703x; 1.0703x over previous
//
#include <hip/hip_runtime.h>
#include <hip/hip_bf16.h>
#include <stdint.h>

// ---------------------------------------------------------------------------
// CustomConvLayer: out[b,o,h,w] = sum_{c,dh,dw} xpad[b,c,h+dh,w+dw] * W[o,c,dh*3+dw]
// Implicit-im2col GEMM, bf16 MFMA 16x16x32. M=B*H*W, N=128, K=576.
//
// R6: revert to the SPLIT structure (R5's fused in-kernel transpose measured
// 98.9us, MfmaUtil 15%, Occ 18% -- serialized scalar-LDS transpose, unhideable
// at 2 blocks/CU; the split xform_x does the same transpose at full-GPU BW).
// On top of R3's proven conv geometry (1 row/block, 256thr, XOR-swizzled
// Aslab, 18-step MFMA loop) add counted-vmcnt staging: Aslab padded to 3328
// chunks (53.2KB, still 3 blocks/CU), staged as 13 guard-free 256-thread
// global_load_lds units (wave-invariant vmcnt counts; tail sources clamped
// per-lane into valid slab, landing in never-read pad slots). Waits:
//   issue 13 units -> vmcnt(8)+bar -> dh=0 -> vmcnt(4)+bar -> dh=1
//   -> vmcnt(0)+bar -> dh=2
// so slab rows 1-2 load UNDER the dh=0 MFMAs (R3 drained everything first).
// In-order vmcnt retirement keeps counts safe despite BtF loads in flight.
// Epilogue: plain stores (R5's nontemporal inflated WRITE_SIZE 186.7 vs
// 134MB). xform_w fused into xform_x (one launch fewer).
// ---------------------------------------------------------------------------

typedef __bf16 bf16x8 __attribute__((ext_vector_type(8)));
typedef float  f32x4  __attribute__((ext_vector_type(4)));

#define GLD_TO_LDS16(g, l)                                                        \
  __builtin_amdgcn_global_load_lds((const __attribute__((address_space(1))) void*)(g), \
                                   (__attribute__((address_space(3))) void*)(l), 16, 0, 0)

// ---- x NCHW fp32 -> padded NHWC bf16 (+ fused border zeroing + weight pack)
// Weight pack (blocks 0..35): BtF chunk(s,quad,n)[r] = W[n][c][tap],
//   k = s*32+quad*8+r, tap=k>>6, c=k&63.
__global__ __launch_bounds__(256) void xform_xw(const float* __restrict__ x,
                                                const float* __restrict__ wgt,
                                                __bf16* __restrict__ xpad,
                                                __bf16* __restrict__ BtF) {
  __shared__ float tile[64][129];  // +1 pad: write phase reads column-wise
  const int tid = threadIdx.x;
  const int b = blockIdx.x >> 7;
  const int h = blockIdx.x & 127;

  // ---- fused weight pack (first 36 blocks, 9216 chunks total)
  {
    const int t = blockIdx.x * 256 + tid;
    if (t < 9216) {
      const int s = t >> 9, rem = t & 511, quad = rem >> 7, n = rem & 127;
      bf16x8 o;
#pragma unroll
      for (int r = 0; r < 8; ++r) {
        const int k = s * 32 + quad * 8 + r;
        const int tap = k >> 6, c = k & 63;
        o[r] = (__bf16)wgt[(n * 64 + c) * 9 + tap];
      }
      *(bf16x8*)(BtF + (size_t)t * 8) = o;
    }
  }

  // ---- border zeroing (independent stores)
  const bf16x8 z8 = {};
  __bf16* prow = xpad + (size_t)(b * 130 + h + 1) * 8320;  // row hp=h+1
  if (tid < 8)        *(bf16x8*)(prow + tid * 8) = z8;               // wp=0
  else if (tid < 16)  *(bf16x8*)(prow + 8256 + (tid - 8) * 8) = z8;  // wp=129
  if (h == 0) {
    bf16x8* r0 = (bf16x8*)(xpad + (size_t)(b * 130) * 8320);         // row hp=0
    for (int i = tid; i < 1040; i += 256) r0[i] = z8;
  } else if (h == 127) {
    bf16x8* r129 = (bf16x8*)(xpad + (size_t)(b * 130 + 129) * 8320); // row hp=129
    for (int i = tid; i < 1040; i += 256) r129[i] = z8;
  }

  const float* src = x + (((size_t)b * 64) * 128 + h) * 128;  // + c*128*128 + w
  for (int i = tid; i < 2048; i += 256) {            // 2048 float4 reads
    const int c = i >> 5, w4 = i & 31;
    f32x4 v = *(const f32x4*)(src + (size_t)c * 16384 + w4 * 4);
    tile[c][w4 * 4 + 0] = v[0];
    tile[c][w4 * 4 + 1] = v[1];
    tile[c][w4 * 4 + 2] = v[2];
    tile[c][w4 * 4 + 3] = v[3];
  }
  __syncthreads();
  __bf16* dst = xpad + ((size_t)(b * 130 + h + 1) * 130 + 1) * 64;
  for (int i = tid; i < 1024; i += 256) {            // 1024 bf16x8 stores
    const int w = i >> 3, cg = i & 7;
    bf16x8 o;
#pragma unroll
    for (int r = 0; r < 8; ++r) o[r] = (__bf16)tile[cg * 8 + r][w];
    *(bf16x8*)(dst + (size_t)w * 64 + cg * 8) = o;
  }
}

// ---------------- main GEMM: block=(b,h), pipelined staging, R3 fragment math
__global__ __launch_bounds__(256) void conv_mfma(const __bf16* __restrict__ xpad,
                                                 const __bf16* __restrict__ BtF,
                                                 float* __restrict__ out) {
  __shared__ alignas(16) __bf16 Aslab[3328 * 8];  // 53,248 B (3120 used + pad); 3 blocks/CU
  const int tid  = threadIdx.x;
  const int lane = tid & 63;
  const int wave = tid >> 6;
  const int quad = lane >> 4;
  const int l16  = lane & 15;
  // XCD-aware swizzle: same-XCD blocks get contiguous (b,h) -> slab-row L2 reuse
  const int rank = (blockIdx.x & 7) * 256 + (blockIdx.x >> 3);
  const int b = rank >> 7;
  const int h = rank & 127;
  const int wm = wave >> 1;  // M half
  const int wn = wave & 1;   // N half

  // ---- stage 3-row slab as 13 uniform units (no guards: wave-invariant vmcnt).
  // LDS chunk l holds source chunk (l&~7) | ((l&7) ^ ((l>>3)&7)); tail units'
  // out-of-range sources clamp per-lane to row 389 (junk lands in pad slots).
  const __bf16* slab = xpad + ((size_t)(b * 130 + h) * 130) * 64;
#define STAGE_UNIT(U) do {                                                \
    const int l_   = ((U) << 8) + tid;                                    \
    const int v_   = l_ >> 3;                                             \
    const int vc_  = v_ > 389 ? 389 : v_;                                 \
    const int cqs_ = (l_ & 7) ^ (v_ & 7);                                 \
    GLD_TO_LDS16(slab + vc_ * 64 + cqs_ * 8,                              \
                 (char*)Aslab + ((((U) << 2) + wave) << 10));             \
  } while (0)

#pragma unroll
  for (int u = 0; u < 13; ++u) STAGE_UNIT(u);
  __builtin_amdgcn_sched_barrier(0);

  f32x4 acc[4][4] = {};

  // one K-phase per dh (slab row dh): 3 dw x 2 half = 6 s-steps, 16 MFMA each
#define PHASE(DH)                                                              \
  _Pragma("unroll")                                                            \
  for (int dw = 0; dw < 3; ++dw) {                                             \
    _Pragma("unroll")                                                          \
    for (int half = 0; half < 2; ++half) {                                     \
      const int s_  = ((DH) * 3 + dw) * 2 + half;                              \
      const int cq_ = (half << 2) + quad;                                      \
      bf16x8 aF[4], bF[4]; /* plain locals, constant-indexed (SROA) */         \
      _Pragma("unroll")                                                        \
      for (int i = 0; i < 4; ++i) {                                            \
        const int m_    = (wm << 6) + (i << 4) + l16;                          \
        const int v_    = (DH) * 130 + m_ + dw;                                \
        const int slot_ = (v_ << 3) + (cq_ ^ (v_ & 7));                        \
        aF[i] = *(const bf16x8*)(Aslab + (size_t)slot_ * 8);                   \
        const int n_ = (wn << 6) + (i << 4) + l16;                             \
        bF[i] = *(const bf16x8*)(BtF + ((size_t)((s_ * 4 + quad) * 128 + n_) << 3)); \
      }                                                                        \
      _Pragma("unroll")                                                        \
      for (int i = 0; i < 4; ++i)                                              \
        _Pragma("unroll")                                                      \
        for (int j = 0; j < 4; ++j)                                            \
          acc[i][j] = __builtin_amdgcn_mfma_f32_16x16x32_bf16(aF[i], bF[j],    \
                                                              acc[i][j], 0, 0, 0); \
    }                                                                          \
  }

  // dh=0 needs units 0..4 (row 0): allow 8 outstanding (units 5..12)
  asm volatile("s_waitcnt vmcnt(8)" ::: "memory");
  __builtin_amdgcn_s_barrier();
  __builtin_amdgcn_sched_barrier(0);
  PHASE(0)
  // dh=1 needs units 0..8 (row 1 ends at chunk 2079 < 2304): allow 4
  asm volatile("s_waitcnt vmcnt(4)" ::: "memory");
  __builtin_amdgcn_s_barrier();
  __builtin_amdgcn_sched_barrier(0);
  PHASE(1)
  // dh=2: drain
  asm volatile("s_waitcnt vmcnt(0)" ::: "memory");
  __builtin_amdgcn_s_barrier();
  __builtin_amdgcn_sched_barrier(0);
  PHASE(2)

  // epilogue: D col = lane&15 = n, row = quad*4+reg = m (out w). Plain stores.
#pragma unroll
  for (int j = 0; j < 4; ++j) {
    const int n = (wn << 6) + (j << 4) + l16;
    float* orow = out + (((size_t)(b * 128 + n) * 128 + h) << 7);
#pragma unroll
    for (int i = 0; i < 4; ++i) {
      const int m0 = (wm << 6) + (i << 4) + (quad << 2);
      *(f32x4*)(orow + m0) = acc[i][j];  // quads 0..3 tile one 64B line per n
    }
  }
}

// ---------------- fallback (if workspace too small): direct fp32 conv -------
__global__ void conv_naive(const float* __restrict__ x, const float* __restrict__ wgt,
                           float* __restrict__ out, int total) {
  int idx = blockIdx.x * 256 + threadIdx.x;
  if (idx >= total) return;
  const int w = idx & 127;
  const int h = (idx >> 7) & 127;
  const int o = (idx >> 14) & 127;
  const int b = idx >> 21;
  float s = 0.f;
  for (int c = 0; c < 64; ++c) {
    const float* xc = x + ((size_t)(b * 64 + c) * 128) * 128;
    const float* wc = wgt + (o * 64 + c) * 9;
    for (int dh = 0; dh < 3; ++dh) {
      const int hh = h + dh - 1;
      if (hh < 0 || hh >= 128) continue;
      for (int dw = 0; dw < 3; ++dw) {
        const int ww = w + dw - 1;
        if (ww < 0 || ww >= 128) continue;
        s += xc[hh * 128 + ww] * wc[dh * 3 + dw];
      }
    }
  }
  out[idx] = s;
}

extern "C" void kernel_launch(void* const* d_in, const int* in_sizes, int n_in,
                              void* d_out, int out_size, void* d_ws, size_t ws_size,
                              hipStream_t stream) {
  const float* x   = (const float*)d_in[0];
  const float* wgt = (const float*)d_in[1];
  float* out = (float*)d_out;

  const size_t BTF_BYTES  = 9216ull * 16;                             // 147456
  const size_t XPAD_BYTES = 16ull * 130 * 130 * 64 * sizeof(__bf16);  // 34.6 MB

  if (ws_size < BTF_BYTES + XPAD_BYTES) {
    const int total = 16 * 128 * 128 * 128;
    conv_naive<<<(total + 255) / 256, 256, 0, stream>>>(x, wgt, out, total);
    return;
  }

  __bf16* BtF  = (__bf16*)d_ws;
  __bf16* xpad = (__bf16*)((char*)d_ws + BTF_BYTES);

  xform_xw<<<16 * 128, 256, 0, stream>>>(x, wgt, xpad, BtF);  // borders+weights fused
  conv_mfma<<<16 * 128, 256, 0, stream>>>(xpad, BtF, out);
}

// Round 4
// 214.604 us; speedup vs baseline: 1.0754x; 1.0048x over previous
//
#include <hip/hip_runtime.h>
#include <hip/hip_bf16.h>
#include <stdint.h>

// ---------------------------------------------------------------------------
// CustomConvLayer: out[b,o,h,w] = sum_{c,dh,dw} xpad[b,c,h+dh,w+dw] * W[o,c,dh*3+dw]
// Implicit-im2col GEMM, bf16 MFMA 16x16x32. M=B*H*W, N=128, K=576.
//
// R7: fully LDS-fed main loop. R6 post-mortem: the counted-vmcnt staging
// pipeline was defeated by in-loop BtF REGISTER loads -- vmcnt is one in-order
// FIFO, and the compiler's implicit wait before the first bF-consuming MFMA
// (N counts only ops issued after bF) force-drained all earlier stage loads.
// Fix: BtF is consumed via LDS too. Per-step 8KB BtF slices (contiguous in
// BtF) are staged into a 3-slot LDS ring through the SAME global_load_lds
// issue stream as the Aslab units, with hand-counted per-step vmcnt waits:
//   prologue: A0-4, S0, S1, A5-8, S2, A9-12   (19 ops)
//   step s:   vmcnt(N_s); s_barrier; issue S_{s+2} (s=1..15); ds_reads; 16 MFMA
//   N = 12,10,6,2,2,...,2,2,0
// Slice s+2 lands in ring slot (s-1)%3 whose step-(s-1) readers finished
// before bar(s). Zero in-loop VMEM reg loads => compiler inserts no vmcnt in
// the loop => loads genuinely stay in flight under MFMAs. LDS 77,824 B ->
// 2 blocks/CU (8 waves): one block's prologue/epilogue overlaps the other's
// compute. BtF per block: one linear 147KB staged copy (was 294KB of
// scattered 16B register loads).
// ---------------------------------------------------------------------------

typedef __bf16 bf16x8 __attribute__((ext_vector_type(8)));
typedef float  f32x4  __attribute__((ext_vector_type(4)));

#define GLD_TO_LDS16(g, l)                                                        \
  __builtin_amdgcn_global_load_lds((const __attribute__((address_space(1))) void*)(g), \
                                   (__attribute__((address_space(3))) void*)(l), 16, 0, 0)

// ---- x NCHW fp32 -> padded NHWC bf16 (+ fused border zeroing + weight pack)
__global__ __launch_bounds__(256) void xform_xw(const float* __restrict__ x,
                                                const float* __restrict__ wgt,
                                                __bf16* __restrict__ xpad,
                                                __bf16* __restrict__ BtF) {
  __shared__ float tile[64][129];  // +1 pad: write phase reads column-wise
  const int tid = threadIdx.x;
  const int b = blockIdx.x >> 7;
  const int h = blockIdx.x & 127;

  // ---- fused weight pack (first 36 blocks, 9216 chunks total)
  // chunk(s,quad,n)[r] = W[n][c][tap], k = s*32+quad*8+r, tap=k>>6, c=k&63
  {
    const int t = blockIdx.x * 256 + tid;
    if (t < 9216) {
      const int s = t >> 9, rem = t & 511, quad = rem >> 7, n = rem & 127;
      bf16x8 o;
#pragma unroll
      for (int r = 0; r < 8; ++r) {
        const int k = s * 32 + quad * 8 + r;
        const int tap = k >> 6, c = k & 63;
        o[r] = (__bf16)wgt[(n * 64 + c) * 9 + tap];
      }
      *(bf16x8*)(BtF + (size_t)t * 8) = o;
    }
  }

  // ---- border zeroing (independent stores)
  const bf16x8 z8 = {};
  __bf16* prow = xpad + (size_t)(b * 130 + h + 1) * 8320;  // row hp=h+1
  if (tid < 8)        *(bf16x8*)(prow + tid * 8) = z8;               // wp=0
  else if (tid < 16)  *(bf16x8*)(prow + 8256 + (tid - 8) * 8) = z8;  // wp=129
  if (h == 0) {
    bf16x8* r0 = (bf16x8*)(xpad + (size_t)(b * 130) * 8320);         // row hp=0
    for (int i = tid; i < 1040; i += 256) r0[i] = z8;
  } else if (h == 127) {
    bf16x8* r129 = (bf16x8*)(xpad + (size_t)(b * 130 + 129) * 8320); // row hp=129
    for (int i = tid; i < 1040; i += 256) r129[i] = z8;
  }

  const float* src = x + (((size_t)b * 64) * 128 + h) * 128;  // + c*128*128 + w
  for (int i = tid; i < 2048; i += 256) {            // 2048 float4 reads
    const int c = i >> 5, w4 = i & 31;
    f32x4 v = *(const f32x4*)(src + (size_t)c * 16384 + w4 * 4);
    tile[c][w4 * 4 + 0] = v[0];
    tile[c][w4 * 4 + 1] = v[1];
    tile[c][w4 * 4 + 2] = v[2];
    tile[c][w4 * 4 + 3] = v[3];
  }
  __syncthreads();
  __bf16* dst = xpad + ((size_t)(b * 130 + h + 1) * 130 + 1) * 64;
  for (int i = tid; i < 1024; i += 256) {            // 1024 bf16x8 stores
    const int w = i >> 3, cg = i & 7;
    bf16x8 o;
#pragma unroll
    for (int r = 0; r < 8; ++r) o[r] = (__bf16)tile[cg * 8 + r][w];
    *(bf16x8*)(dst + (size_t)w * 64 + cg * 8) = o;
  }
}

// ---------------- main GEMM: block=(b,h); LDS-fed loop with slice ring ------
__global__ __launch_bounds__(256) void conv_mfma(const __bf16* __restrict__ xpad,
                                                 const __bf16* __restrict__ BtF,
                                                 float* __restrict__ out) {
  // chunks 0..3327: Aslab (3120 used + uniform-unit pad); 3328..4863: BtF ring (3 x 512)
  __shared__ alignas(16) __bf16 Aslab[4864 * 8];  // 77,824 B -> 2 blocks/CU
  const int tid  = threadIdx.x;
  const int lane = tid & 63;
  const int wave = tid >> 6;
  const int quad = lane >> 4;
  const int l16  = lane & 15;
  // XCD-aware swizzle: same-XCD blocks get contiguous (b,h) -> slab-row L2 reuse
  const int rank = (blockIdx.x & 7) * 256 + (blockIdx.x >> 3);
  const int b = rank >> 7;
  const int h = rank & 127;
  const int wm = wave >> 1;  // M half
  const int wn = wave & 1;   // N half

  const __bf16* slab = xpad + ((size_t)(b * 130 + h) * 130) * 64;

  // A-unit U (U=0..12): 256 chunks; LDS chunk l holds source chunk
  // (l&~7)|((l&7)^((l>>3)&7)); tail clamps to row 389 (junk -> pad slots)
#define STAGE_A(U) do {                                                   \
    const int l_   = ((U) << 8) + tid;                                    \
    const int v_   = l_ >> 3;                                             \
    const int vc_  = v_ > 389 ? 389 : v_;                                 \
    const int cqs_ = (l_ & 7) ^ (v_ & 7);                                 \
    GLD_TO_LDS16(slab + vc_ * 64 + cqs_ * 8,                              \
                 (char*)Aslab + ((((U) << 2) + wave) << 10));             \
  } while (0)

  // BtF slice K (8KB, contiguous: chunks K*512..K*512+511) unit U (U=0,1)
  // -> ring slot K%3, stored LINEAR (contiguous 16-lane reads: conflict-free)
#define STAGE_S(K, U) do {                                                \
    const int c_ = ((U) << 8) + (wave << 6) + lane;                       \
    GLD_TO_LDS16(BtF + ((size_t)(((K) << 9) + c_) << 3),                  \
                 (char*)Aslab + ((3328 + (((K) % 3) << 9) + ((U) << 8) + (wave << 6)) << 4)); \
  } while (0)

  // ---- prologue issue stream (19 ops; order defines the vmcnt ledger)
  STAGE_A(0); STAGE_A(1); STAGE_A(2); STAGE_A(3); STAGE_A(4);   // row 0
  STAGE_S(0, 0); STAGE_S(0, 1);                                 // slice 0
  STAGE_S(1, 0); STAGE_S(1, 1);                                 // slice 1
  STAGE_A(5); STAGE_A(6); STAGE_A(7); STAGE_A(8);               // row 1
  STAGE_S(2, 0); STAGE_S(2, 1);                                 // slice 2
  STAGE_A(9); STAGE_A(10); STAGE_A(11); STAGE_A(12);            // row 2
  __builtin_amdgcn_sched_barrier(0);

  f32x4 acc[4][4] = {};

  // step S: dh=S/6, dw=(S%6)/2, half=S&1. Needs A-row dh + slice S.
  // Issue S_{S+2} (S=1..15) after bar(S): targets ring slot (S-1)%3 whose
  // step-(S-1) readers completed before this barrier.
#define STEP(S, VM) do {                                                       \
    asm volatile("s_waitcnt vmcnt(" #VM ")" ::: "memory");                     \
    __builtin_amdgcn_s_barrier();                                              \
    __builtin_amdgcn_sched_barrier(0);                                         \
    if ((S) >= 1 && (S) <= 15) { STAGE_S((S) + 2, 0); STAGE_S((S) + 2, 1); }   \
    __builtin_amdgcn_sched_barrier(0);                                         \
    {                                                                          \
      const int dh_ = (S) / 6, dw_ = ((S) % 6) >> 1, half_ = (S) & 1;          \
      const int cq_ = (half_ << 2) + quad;                                     \
      bf16x8 aF[4], bF[4]; /* plain locals, constant-indexed (SROA) */         \
      _Pragma("unroll")                                                        \
      for (int i = 0; i < 4; ++i) {                                            \
        const int m_    = (wm << 6) + (i << 4) + l16;                          \
        const int v_    = dh_ * 130 + m_ + dw_;                                \
        const int slot_ = (v_ << 3) + (cq_ ^ (v_ & 7));                        \
        aF[i] = *(const bf16x8*)(Aslab + (size_t)slot_ * 8);                   \
        bF[i] = *(const bf16x8*)(Aslab +                                       \
            ((size_t)(3328 + (((S) % 3) << 9) + (quad << 7) + (wn << 6) +      \
                      (i << 4) + l16) << 3));                                  \
      }                                                                        \
      _Pragma("unroll")                                                        \
      for (int i = 0; i < 4; ++i)                                              \
        _Pragma("unroll")                                                      \
        for (int j = 0; j < 4; ++j)                                            \
          acc[i][j] = __builtin_amdgcn_mfma_f32_16x16x32_bf16(aF[i], bF[j],    \
                                                              acc[i][j], 0, 0, 0); \
    }                                                                          \
  } while (0)

  // vmcnt ledger: T(pre-wait issued) - P(prefix needed) [see header comment]
  STEP(0, 12);  STEP(1, 10);  STEP(2, 6);
  STEP(3, 2);   STEP(4, 2);   STEP(5, 2);
  STEP(6, 2);   STEP(7, 2);   STEP(8, 2);
  STEP(9, 2);   STEP(10, 2);  STEP(11, 2);
  STEP(12, 2);  STEP(13, 2);  STEP(14, 2);
  STEP(15, 2);  STEP(16, 2);  STEP(17, 0);

  // epilogue: D col = lane&15 = n, row = quad*4+reg = m (out w). Plain stores.
#pragma unroll
  for (int j = 0; j < 4; ++j) {
    const int n = (wn << 6) + (j << 4) + l16;
    float* orow = out + (((size_t)(b * 128 + n) * 128 + h) << 7);
#pragma unroll
    for (int i = 0; i < 4; ++i) {
      const int m0 = (wm << 6) + (i << 4) + (quad << 2);
      *(f32x4*)(orow + m0) = acc[i][j];  // quads 0..3 tile one 64B line per n
    }
  }
}

// ---------------- fallback (if workspace too small): direct fp32 conv -------
__global__ void conv_naive(const float* __restrict__ x, const float* __restrict__ wgt,
                           float* __restrict__ out, int total) {
  int idx = blockIdx.x * 256 + threadIdx.x;
  if (idx >= total) return;
  const int w = idx & 127;
  const int h = (idx >> 7) & 127;
  const int o = (idx >> 14) & 127;
  const int b = idx >> 21;
  float s = 0.f;
  for (int c = 0; c < 64; ++c) {
    const float* xc = x + ((size_t)(b * 64 + c) * 128) * 128;
    const float* wc = wgt + (o * 64 + c) * 9;
    for (int dh = 0; dh < 3; ++dh) {
      const int hh = h + dh - 1;
      if (hh < 0 || hh >= 128) continue;
      for (int dw = 0; dw < 3; ++dw) {
        const int ww = w + dw - 1;
        if (ww < 0 || ww >= 128) continue;
        s += xc[hh * 128 + ww] * wc[dh * 3 + dw];
      }
    }
  }
  out[idx] = s;
}

extern "C" void kernel_launch(void* const* d_in, const int* in_sizes, int n_in,
                              void* d_out, int out_size, void* d_ws, size_t ws_size,
                              hipStream_t stream) {
  const float* x   = (const float*)d_in[0];
  const float* wgt = (const float*)d_in[1];
  float* out = (float*)d_out;

  const size_t BTF_BYTES  = 9216ull * 16;                             // 147456
  const size_t XPAD_BYTES = 16ull * 130 * 130 * 64 * sizeof(__bf16);  // 34.6 MB

  if (ws_size < BTF_BYTES + XPAD_BYTES) {
    const int total = 16 * 128 * 128 * 128;
    conv_naive<<<(total + 255) / 256, 256, 0, stream>>>(x, wgt, out, total);
    return;
  }

  __bf16* BtF  = (__bf16*)d_ws;
  __bf16* xpad = (__bf16*)((char*)d_ws + BTF_BYTES);

  xform_xw<<<16 * 128, 256, 0, stream>>>(x, wgt, xpad, BtF);  // borders+weights fused
  conv_mfma<<<16 * 128, 256, 0, stream>>>(xpad, BtF, out);
}